// Round 7
// baseline (4446.765 us; speedup 1.0000x reference)
//
#include <hip/hip_runtime.h>
#include <hip/hip_bf16.h>
#include <cstdint>
#include <cstddef>

#define BB 256
#define TT 20
#define NOBJ 36
#define OBJD 2048
#define ATTD 1024
#define DECD 1024
#define VOCAB 10000
#define NBIG   17168   // 7168 (Wda|Wfb|Whh-interleaved) + 10000 (Wfc)
#define NBIGP2 17408   // 136 panels of 128
#define NSPLIT 7168
#define NGRID  512     // persistent blocks (2 per CU guaranteed)

typedef unsigned short u16;
typedef __attribute__((ext_vector_type(8))) short short8v;
typedef __attribute__((ext_vector_type(4))) float f32x4;
typedef __attribute__((ext_vector_type(2))) unsigned int u32x2;

__device__ inline u16 f2bf(float f) {
    __hip_bfloat16 h = __float2bfloat16(f);
    return *reinterpret_cast<u16*>(&h);
}
__device__ inline float bu(u16 u) {
    union { unsigned int i; float f; } x;
    x.i = ((unsigned int)u) << 16;
    return x.f;
}
__device__ inline float sigf(float x) { return 1.f / (1.f + expf(-x)); }

// ---- explicit device-coherent (sc0|sc1 = bypass L1+L2, at MALL) helpers ----
__device__ inline void st_u16_sc(u16* p, u16 v) {
    unsigned vv = v;
    asm volatile("global_store_short %0, %1, off sc0 sc1" :: "v"(p), "v"(vv) : "memory");
}
__device__ inline void st_u32_sc(void* p, unsigned v) {
    asm volatile("global_store_dword %0, %1, off sc0 sc1" :: "v"(p), "v"(v) : "memory");
}
__device__ inline void st_f32_sc(float* p, float v) {
    asm volatile("global_store_dword %0, %1, off sc0 sc1" :: "v"(p), "v"(v) : "memory");
}
__device__ inline void st_u64_sc(void* p, u32x2 v) {
    asm volatile("global_store_dwordx2 %0, %1, off sc0 sc1" :: "v"(p), "v"(v) : "memory");
}
__device__ inline void st_f4_sc(float* p, f32x4 v) {
    asm volatile("global_store_dwordx4 %0, %1, off sc0 sc1" :: "v"(p), "v"(v) : "memory");
}
__device__ inline unsigned ld_u32_sc(const int* p) {
    unsigned r;
    asm volatile("global_load_dword %0, %1, off sc0 sc1\n\ts_waitcnt vmcnt(0)"
                 : "=v"(r) : "v"(p) : "memory");
    return r;
}
__device__ inline f32x4 ld_f4_sc(const float* p) {
    f32x4 r;
    asm volatile("global_load_dwordx4 %0, %1, off sc0 sc1\n\ts_waitcnt vmcnt(0)"
                 : "=v"(r) : "v"(p) : "memory");
    return r;
}
__device__ inline void ld2_f4_sc(const float* p0, const float* p1, f32x4& a, f32x4& b) {
    asm volatile("global_load_dwordx4 %0, %2, off sc0 sc1\n\t"
                 "global_load_dwordx4 %1, %3, off sc0 sc1\n\t"
                 "s_waitcnt vmcnt(0)"
                 : "=&v"(a), "=&v"(b) : "v"(p0), "v"(p1) : "memory");
}
__device__ inline void ld4_f4_sc(const float* p, f32x4& a, f32x4& b, f32x4& c, f32x4& d) {
    asm volatile("global_load_dwordx4 %0, %4, off sc0 sc1\n\t"
                 "global_load_dwordx4 %1, %4, off offset:16 sc0 sc1\n\t"
                 "global_load_dwordx4 %2, %4, off offset:32 sc0 sc1\n\t"
                 "global_load_dwordx4 %3, %4, off offset:48 sc0 sc1\n\t"
                 "s_waitcnt vmcnt(0)"
                 : "=&v"(a), "=&v"(b), "=&v"(c), "=&v"(d) : "v"(p) : "memory");
}

// async global->LDS, 16B/lane. AUX: 0 = cached, 17 = SC0|SC1 (device-coherent)
template<int AUX>
__device__ inline void gload16(const u16* g, u16* l) {
    __builtin_amdgcn_global_load_lds(
        (const __attribute__((address_space(1))) unsigned int*)g,
        (__attribute__((address_space(3))) unsigned int*)l, 16, 0, AUX);
}

struct MegaParams {
    const float* enc; const float* objs; const int* caps; const int* clen;
    const float* emb;
    const float* Wea; const float* bea; const float* Wda; const float* bda;
    const float* wfa; const float* bfa; const float* Wfb; const float* bfb;
    const float* Wih; const float* Whh; const float* bih; const float* bhh;
    const float* Wfc; const float* bfc;
    float* outP; float* out_caps; float* out_len; float* out_alph; float* out_sind;
    int* bar; int* sidx; int* slen; int* cnt;
    u16* objsb; u16* Wbigb; float* bcat; u16* Wihb; float* bsum; u16* Weab;
    u16* att1b; u16* Xb; u16* Gxb; float* Hcat; u16* aweb; float* G2p;
    float* c; u16* hb;
};

// ---------------------------------------------------------------------------
// Grid barrier: arrival = agent-scope RMW (coherence point); release = sc
// store; spin = sc load (bypasses L2 -> cannot be stale). Bounded spin as
// anti-hang insurance. __syncthreads drains each wave's vmem before arrival.
// ---------------------------------------------------------------------------
__device__ inline void grid_bar(int* bar, int& ep) {
    __syncthreads();
    if (threadIdx.x == 0) {
        ++ep;
        const int prev = __hip_atomic_fetch_add(&bar[0], 1, __ATOMIC_RELAXED,
                                                __HIP_MEMORY_SCOPE_AGENT);
        if (prev == NGRID * ep - 1) {
            st_u32_sc(&bar[1], (unsigned)ep);
        } else {
            int guard = 0;
            while ((int)ld_u32_sc(&bar[1]) < ep && ++guard < (1 << 18))
                __builtin_amdgcn_s_sleep(8);
        }
    }
    __syncthreads();
}

// ---------------------------------------------------------------------------
// 128x128xK GEMM core. Asymmetric pipeline: A 6-deep, B 3-deep, uniform
// s_waitcnt vmcnt(10), clamped tail prefetch. LDS: A 6x8KB + B 3x8KB = 72KB.
// Source-pre-swizzled global_load_lds (LDS linear) + swizzled ds_read_b128.
// Requires K % 32 == 0, K/32 >= 6.
// ---------------------------------------------------------------------------
template<int AUXA, int AUXB>
__device__ void gemm_core(u16* SH,
    const u16* __restrict__ A, int lda,
    const u16* __restrict__ B, int ldb,
    int K, int m0, int n0, f32x4 acc[4][4])
{
    u16* AsB = SH;                 // 6 slots x 4096 u16
    u16* BsB = SH + 6 * 4096;      // 3 slots x 4096 u16
    const int tid = threadIdx.x;
    const int lane = tid & 63;
    const int w = tid >> 6;
    const int wr = w >> 1, wc = w & 1;

    const int r0 = (w * 2 + 0) * 16 + (lane >> 2);
    const int r1 = (w * 2 + 1) * 16 + (lane >> 2);
    const int s0 = (lane & 3) ^ ((r0 >> 1) & 3);
    const int s1 = (lane & 3) ^ ((r1 >> 1) & 3);
    const u16* gA0 = A + (size_t)(m0 + r0) * lda + s0 * 8;
    const u16* gA1 = A + (size_t)(m0 + r1) * lda + s1 * 8;
    const u16* gB0 = B + (size_t)(n0 + r0) * ldb + s0 * 8;
    const u16* gB1 = B + (size_t)(n0 + r1) * ldb + s1 * 8;
    const int la0 = (w * 2 + 0) * 512;
    const int la1 = (w * 2 + 1) * 512;

    int ia[4], ib[4];
    #pragma unroll
    for (int mi = 0; mi < 4; ++mi) {
        const int r = wr * 64 + mi * 16 + (lane & 15);
        ia[mi] = r * 32 + (((lane >> 4) ^ ((r >> 1) & 3)) << 3);
    }
    #pragma unroll
    for (int nj = 0; nj < 4; ++nj) {
        const int r = wc * 64 + nj * 16 + (lane & 15);
        ib[nj] = r * 32 + (((lane >> 4) ^ ((r >> 1) & 3)) << 3);
    }

    const int nk = K >> 5;
    // prologue FIFO: A0 A1 A2 B0 A3 B1 A4 B2 A5 (2 instr each -> 18 entries)
    gload16<AUXA>(gA0 + 0 * 32, AsB + 0 * 4096 + la0);
    gload16<AUXA>(gA1 + 0 * 32, AsB + 0 * 4096 + la1);
    gload16<AUXA>(gA0 + 1 * 32, AsB + 1 * 4096 + la0);
    gload16<AUXA>(gA1 + 1 * 32, AsB + 1 * 4096 + la1);
    gload16<AUXA>(gA0 + 2 * 32, AsB + 2 * 4096 + la0);
    gload16<AUXA>(gA1 + 2 * 32, AsB + 2 * 4096 + la1);
    gload16<AUXB>(gB0 + 0 * 32, BsB + 0 * 4096 + la0);
    gload16<AUXB>(gB1 + 0 * 32, BsB + 0 * 4096 + la1);
    gload16<AUXA>(gA0 + 3 * 32, AsB + 3 * 4096 + la0);
    gload16<AUXA>(gA1 + 3 * 32, AsB + 3 * 4096 + la1);
    gload16<AUXB>(gB0 + 1 * 32, BsB + 1 * 4096 + la0);
    gload16<AUXB>(gB1 + 1 * 32, BsB + 1 * 4096 + la1);
    gload16<AUXA>(gA0 + 4 * 32, AsB + 4 * 4096 + la0);
    gload16<AUXA>(gA1 + 4 * 32, AsB + 4 * 4096 + la1);
    gload16<AUXB>(gB0 + 2 * 32, BsB + 2 * 4096 + la0);
    gload16<AUXB>(gB1 + 2 * 32, BsB + 2 * 4096 + la1);
    gload16<AUXA>(gA0 + 5 * 32, AsB + 5 * 4096 + la0);
    gload16<AUXA>(gA1 + 5 * 32, AsB + 5 * 4096 + la1);

    int sa = 0, sb = 0;            // LDS slot cursors (it % 6, it % 3)
    for (int it = 0; it < nk; ++it) {
        asm volatile("s_waitcnt vmcnt(10)" ::: "memory");
        __builtin_amdgcn_s_barrier();
        const u16* Asc = AsB + sa * 4096;
        const u16* Bsc = BsB + sb * 4096;
        short8v av[4], bv[4];
        #pragma unroll
        for (int mi = 0; mi < 4; ++mi) av[mi] = *(const short8v*)&Asc[ia[mi]];
        #pragma unroll
        for (int nj = 0; nj < 4; ++nj) bv[nj] = *(const short8v*)&Bsc[ib[nj]];
        __builtin_amdgcn_s_setprio(1);
        #pragma unroll
        for (int mi = 0; mi < 4; ++mi)
            #pragma unroll
            for (int nj = 0; nj < 4; ++nj)
                acc[mi][nj] = __builtin_amdgcn_mfma_f32_16x16x32_bf16(
                    av[mi], bv[nj], acc[mi][nj], 0, 0, 0);
        __builtin_amdgcn_s_setprio(0);
        __builtin_amdgcn_s_barrier();
        // push B(it+3) then A(it+6), clamped (dupes land in freed slots)
        {
            const int bt = (it + 3 < nk) ? (it + 3) : (nk - 1);
            const int at = (it + 6 < nk) ? (it + 6) : (nk - 1);
            gload16<AUXB>(gB0 + bt * 32, BsB + sb * 4096 + la0);
            gload16<AUXB>(gB1 + bt * 32, BsB + sb * 4096 + la1);
            gload16<AUXA>(gA0 + at * 32, AsB + sa * 4096 + la0);
            gload16<AUXA>(gA1 + at * 32, AsB + sa * 4096 + la1);
        }
        sa = (sa == 5) ? 0 : sa + 1;
        sb = (sb == 2) ? 0 : sb + 1;
    }
    asm volatile("s_waitcnt vmcnt(0)" ::: "memory");
    __builtin_amdgcn_s_barrier();
}

// Setup epilogue: bf16 C via sc stores (write-once buffers, read cached later)
__device__ void epi_bf16(f32x4 acc[4][4], u16* Cb, int ldc,
                         const float* bias, int m0, int n0)
{
    const int lane = threadIdx.x & 63;
    const int w = threadIdx.x >> 6;
    const int wr = w >> 1, wc = w & 1;
    #pragma unroll
    for (int mi = 0; mi < 4; ++mi) {
        const int mbase = m0 + wr * 64 + mi * 16 + ((lane >> 4) << 2);
        #pragma unroll
        for (int nj = 0; nj < 4; ++nj) {
            const int n = n0 + wc * 64 + nj * 16 + (lane & 15);
            const float bval = bias ? bias[n] : 0.f;   // cached (post-inv)
            #pragma unroll
            for (int r = 0; r < 4; ++r)
                st_u16_sc(&Cb[(size_t)(mbase + r) * ldc + n], f2bf(acc[mi][nj][r] + bval));
        }
    }
}

// ---------------------------------------------------------------------------
// Attention (z-split): block (b = bid&255, z = bid>>8). att1b/objsb cached
// (L2-resident); Hcat via sc (mutable); aweb written sc.
// ---------------------------------------------------------------------------
__device__ void attn_job(const MegaParams& P, int b, int z, int t,
                         float (*wred)[40], float* es, float* alph)
{
    const int tid = threadIdx.x;
    if (t >= P.slen[b]) {
        if (z == 0 && tid < NOBJ)
            P.out_alph[((size_t)b * TT + t) * NOBJ + tid] = 0.f;
        return;
    }
    const int lane = tid & 63, w = tid >> 6;
    const float* hrow = P.Hcat + (size_t)b * 7168;
    f32x4 h4, g0;
    ld2_f4_sc(hrow + tid * 4, hrow + 1024 + z * 1024 + tid * 4, h4, g0);
    const f32x4 w4 = *((const f32x4*)P.wfa + tid);
    const u16* a1base = P.att1b + (size_t)b * NOBJ * ATTD;

    float ep[NOBJ];
    #pragma unroll
    for (int n = 0; n < NOBJ; ++n) {
        ushort4 a4 = ((const ushort4*)(a1base + (size_t)n * ATTD))[tid];
        const float v0 = fmaxf(bu(a4.x) + h4[0], 0.f);
        const float v1 = fmaxf(bu(a4.y) + h4[1], 0.f);
        const float v2 = fmaxf(bu(a4.z) + h4[2], 0.f);
        const float v3 = fmaxf(bu(a4.w) + h4[3], 0.f);
        ep[n] = v0 * w4[0] + v1 * w4[1] + v2 * w4[2] + v3 * w4[3];
    }
    #pragma unroll
    for (int n = 0; n < NOBJ; ++n) {
        float p = ep[n];
        #pragma unroll
        for (int off = 32; off > 0; off >>= 1) p += __shfl_down(p, off, 64);
        if (lane == 0) wred[w][n] = p;
    }
    __syncthreads();
    if (tid < NOBJ)
        es[tid] = wred[0][tid] + wred[1][tid] + wred[2][tid] + wred[3][tid] + P.bfa[0];
    __syncthreads();
    if (tid < 64) {
        float mv = (tid < NOBJ) ? es[tid] : -1e30f;
        #pragma unroll
        for (int off = 32; off > 0; off >>= 1) mv = fmaxf(mv, __shfl_xor(mv, off, 64));
        float e = (tid < NOBJ) ? expf(es[tid] - mv) : 0.f;
        float s = e;
        #pragma unroll
        for (int off = 32; off > 0; off >>= 1) s += __shfl_xor(s, off, 64);
        if (tid < NOBJ) alph[tid] = e / s;
    }
    __syncthreads();
    if (z == 0 && tid < NOBJ)
        P.out_alph[((size_t)b * TT + t) * NOBJ + tid] = alph[tid];

    float acc[4] = {0.f, 0.f, 0.f, 0.f};
    const u16* ob = P.objsb + (size_t)b * NOBJ * OBJD + z * 1024 + tid * 4;
    #pragma unroll 4
    for (int n = 0; n < NOBJ; ++n) {
        const ushort4 ov = *(const ushort4*)(ob + (size_t)n * OBJD);
        const float al = alph[n];
        acc[0] = fmaf(al, bu(ov.x), acc[0]);
        acc[1] = fmaf(al, bu(ov.y), acc[1]);
        acc[2] = fmaf(al, bu(ov.z), acc[2]);
        acc[3] = fmaf(al, bu(ov.w), acc[3]);
    }
    ushort4 st;
    st.x = f2bf(acc[0] * sigf(g0[0]));
    st.y = f2bf(acc[1] * sigf(g0[1]));
    st.z = f2bf(acc[2] * sigf(g0[2]));
    st.w = f2bf(acc[3] * sigf(g0[3]));
    union { ushort4 s; u32x2 u; } cvt; cvt.s = st;
    st_u64_sc(&P.aweb[(size_t)b * 2048 + z * 1024 + tid * 4], cvt.u);
}

// ---------------------------------------------------------------------------
// LSTM: row b = bid. Gate-interleaved (col n = 4d+q). Thread tid owns dims
// 4*tid..4*tid+3. G2p/Hcat via sc; Gxb cached; c block-private cached.
// ---------------------------------------------------------------------------
__device__ void lstm_job(const MegaParams& P, int b, int t)
{
    if (t >= P.slen[b]) return;
    const int tid = threadIdx.x;
    const float* hc = P.Hcat + (size_t)b * 7168 + 3072 + tid * 16;
    f32x4 hv0, hv1, hv2, hv3;
    ld4_f4_sc(hc, hv0, hv1, hv2, hv3);
    float g[16];
    #pragma unroll
    for (int i = 0; i < 4; ++i) {
        g[i] = hv0[i]; g[4 + i] = hv1[i]; g[8 + i] = hv2[i]; g[12 + i] = hv3[i];
    }
    const u16* gx = P.Gxb + ((size_t)(t * BB + b)) * 4096 + tid * 16;   // cached
    #pragma unroll
    for (int i = 0; i < 16; ++i) g[i] += bu(gx[i]);
    #pragma unroll
    for (int p = 0; p < 4; ++p) {
        const float* gp = P.G2p + (size_t)p * (BB * 4096) + (size_t)b * 4096 + tid * 16;
        f32x4 a, bb, cc, dd;
        ld4_f4_sc(gp, a, bb, cc, dd);
        #pragma unroll
        for (int i = 0; i < 4; ++i) {
            g[i] += a[i]; g[4 + i] += bb[i]; g[8 + i] += cc[i]; g[12 + i] += dd[i];
        }
    }
    f32x4 cv = *(f32x4*)(P.c + (size_t)b * 1024 + tid * 4);   // private
    ushort4 hb4;
    #pragma unroll
    for (int dl = 0; dl < 4; ++dl) {
        const float gi = g[dl * 4 + 0], gf = g[dl * 4 + 1];
        const float gg = g[dl * 4 + 2], go = g[dl * 4 + 3];
        const float cn = sigf(gf) * cv[dl] + sigf(gi) * tanhf(gg);
        const float hn = sigf(go) * tanhf(cn);
        cv[dl] = cn;
        ((u16*)&hb4)[dl] = f2bf(hn);
    }
    *(f32x4*)(P.c + (size_t)b * 1024 + tid * 4) = cv;
    union { ushort4 s; u32x2 u; } cvt; cvt.s = hb4;
    st_u64_sc(&P.hb[(size_t)b * 1024 + tid * 4], cvt.u);
}

// ---------------------------------------------------------------------------
// Persistent megakernel.
// ---------------------------------------------------------------------------
__global__ __launch_bounds__(256, 2) void mega(MegaParams P)
{
    __shared__ __align__(16) u16 SH[9 * 4096];   // 72KB (A 6x8KB + B 3x8KB)
    __shared__ float wred[4][40];
    __shared__ float es[40];
    __shared__ float alph[40];
    __shared__ int Ls[BB];
    __shared__ int SLs[BB];
    const int bid = blockIdx.x;
    const int tid = threadIdx.x;
    int ep = 0;

    // ======== S0: flush any pre-kernel dirty L2 lines, then sync
    __builtin_amdgcn_fence(__ATOMIC_RELEASE, "agent");   // wbl2
    grid_bar(P.bar, ep);

    // ======== S1a: sort (block 0) + weight conversions (all sc stores)
    if (bid == 0) {
        const int li = P.clen[tid];
        Ls[tid] = li;
        __syncthreads();
        int r = 0;
        for (int j = 0; j < BB; ++j) {
            const int lj = Ls[j];
            if (lj > li || (lj == li && j < tid)) r++;
        }
        st_u32_sc(&P.sidx[r], (unsigned)tid);
        st_u32_sc(&P.slen[r], (unsigned)li);
        SLs[r] = li;
        st_f32_sc(&P.out_sind[r], (float)tid);
        st_f32_sc(&P.out_len[r], (float)li);
        __syncthreads();
        if (tid < TT) {
            int cc = 0;
            for (int b2 = 0; b2 < BB; ++b2) cc += (SLs[b2] > tid);
            st_u32_sc(&P.cnt[tid], (unsigned)cc);
        }
    }
    // Wbig rows: [Wda | Wfb | Whh-interleaved | Wfc | pad] (17408 x 1024)
    for (int n = bid; n < NBIGP2; n += NGRID) {
        const float* src = nullptr;
        float bbv = 0.f;
        if (n < 1024)      { src = P.Wda + (size_t)n * 1024;          bbv = P.bda[n]; }
        else if (n < 3072) { src = P.Wfb + (size_t)(n - 1024) * 1024; bbv = P.bfb[n - 1024]; }
        else if (n < 7168) {
            const int loc = n - 3072, q = loc & 3, d = loc >> 2;
            src = P.Whh + ((size_t)q * 1024 + d) * 1024;
        }
        else if (n < NBIG) { src = P.Wfc + (size_t)(n - 7168) * 1024; bbv = P.bfc[n - 7168]; }
        ushort4 s4;
        if (src) {
            float4 v = ((const float4*)src)[tid];
            s4.x = f2bf(v.x); s4.y = f2bf(v.y); s4.z = f2bf(v.z); s4.w = f2bf(v.w);
        } else { s4.x = s4.y = s4.z = s4.w = 0; }
        union { ushort4 s; u32x2 u; } cvt; cvt.s = s4;
        st_u64_sc(&P.Wbigb[(size_t)n * 1024 + tid * 4], cvt.u);
        if (tid == 0) st_f32_sc(&P.bcat[n], bbv);
    }
    // Wih gate-interleaved (4096 x 3072) + bsum
    for (int n = bid; n < 4096; n += NGRID) {
        const int q = n & 3, d = n >> 2;
        const float* src = P.Wih + ((size_t)q * 1024 + d) * 3072;
        u16* dst = P.Wihb + (size_t)n * 3072;
        #pragma unroll
        for (int j = 0; j < 3; ++j) {
            float4 v = ((const float4*)src)[tid + 256 * j];
            ushort4 s4;
            s4.x = f2bf(v.x); s4.y = f2bf(v.y); s4.z = f2bf(v.z); s4.w = f2bf(v.w);
            union { ushort4 s; u32x2 u; } cvt; cvt.s = s4;
            st_u64_sc(&dst[(tid + 256 * j) * 4], cvt.u);
        }
        if (tid == 0) st_f32_sc(&P.bsum[n], P.bih[q * 1024 + d] + P.bhh[q * 1024 + d]);
    }
    // Wea (1024 x 2048)
    for (int n = bid; n < 1024; n += NGRID) {
        const float* src = P.Wea + (size_t)n * OBJD;
        u16* dst = P.Weab + (size_t)n * OBJD;
        #pragma unroll
        for (int j = 0; j < 2; ++j) {
            float4 v = ((const float4*)src)[tid + 256 * j];
            ushort4 s4;
            s4.x = f2bf(v.x); s4.y = f2bf(v.y); s4.z = f2bf(v.z); s4.w = f2bf(v.w);
            union { ushort4 s; u32x2 u; } cvt; cvt.s = s4;
            st_u64_sc(&dst[(tid + 256 * j) * 4], cvt.u);
        }
    }
    // zero c (sc; owner lstm block cached-reads it fresh after the inv)
    if (bid < BB)
        st_f4_sc(P.c + (size_t)bid * 1024 + tid * 4, (f32x4){0.f, 0.f, 0.f, 0.f});
    grid_bar(P.bar, ep);

    // ======== S1b: sorted gathers (sidx via sc reads) + Hcat(0)
    for (int row = bid; row < BB * NOBJ; row += NGRID) {
        const int b = row / NOBJ, n = row - b * NOBJ;
        const int sb = (int)ld_u32_sc(&P.sidx[b]);
        const float* src = P.objs + ((size_t)sb * NOBJ + n) * OBJD;
        u16* dst = P.objsb + (size_t)row * OBJD;
        #pragma unroll
        for (int j = 0; j < 2; ++j) {
            float4 v = ((const float4*)src)[tid + 256 * j];
            ushort4 s4;
            s4.x = f2bf(v.x); s4.y = f2bf(v.y); s4.z = f2bf(v.z); s4.w = f2bf(v.w);
            union { ushort4 s; u32x2 u; } cvt; cvt.s = s4;
            st_u64_sc(&dst[(tid + 256 * j) * 4], cvt.u);
        }
    }
    for (int blk = bid; blk < TT * BB; blk += NGRID) {
        const int t = blk >> 8, b = blk & 255;
        const int sb = (int)ld_u32_sc(&P.sidx[b]);
        const float* src = (t == 0) ? (P.enc + (size_t)sb * DECD)
                                    : (P.emb + (size_t)P.caps[sb * TT + (t - 1)] * DECD);
        float4 v = ((const float4*)src)[tid];
        ushort4 s4;
        s4.x = f2bf(v.x); s4.y = f2bf(v.y); s4.z = f2bf(v.z); s4.w = f2bf(v.w);
        union { ushort4 s; u32x2 u; } cvt; cvt.s = s4;
        st_u64_sc(&P.Xb[(size_t)blk * DECD + tid * 4], cvt.u);
    }
    if (bid == 1) {
        for (int i = tid; i < BB * TT; i += 256) {
            const int p = i / TT, t = i % TT;
            const int sb = (int)ld_u32_sc(&P.sidx[p]);
            st_f32_sc(&P.out_caps[i], (float)P.caps[sb * TT + t]);
        }
    }
    if (bid < BB) {   // Hcat(0) = bcat broadcast (h0 = 0); Hcat is sc-class
        float* dst = P.Hcat + (size_t)bid * 7168;
        for (int i = tid; i < 1792; i += 256)
            st_f4_sc(dst + i * 4, ld_f4_sc(P.bcat + i * 4));
    }
    grid_bar(P.bar, ep);

    // ======== one-time L2 invalidate: purge stale lines, then cached reads
    __builtin_amdgcn_fence(__ATOMIC_ACQUIRE, "agent");   // buffer_inv

    // ======== S2: att1 (576 jobs) + Gx (1280 jobs); cached reads, sc writes
    for (int j = bid; j < 576 + 1280; j += NGRID) {
        f32x4 acc[4][4];
        #pragma unroll
        for (int i = 0; i < 4; ++i)
            #pragma unroll
            for (int jj = 0; jj < 4; ++jj) acc[i][jj] = (f32x4){0.f, 0.f, 0.f, 0.f};
        if (j < 576) {
            const int n = j / 72, m = j % 72;
            gemm_core<0, 0>(SH, P.objsb, OBJD, P.Weab, OBJD, OBJD, m * 128, n * 128, acc);
            epi_bf16(acc, P.att1b, ATTD, P.bea, m * 128, n * 128);
        } else {
            const int j2 = j - 576;
            const int n = j2 / 40, m = j2 % 40;
            gemm_core<0, 0>(SH, P.Xb, DECD, P.Wihb, 3072, DECD, m * 128, n * 128, acc);
            epi_bf16(acc, P.Gxb, 4096, P.bsum, m * 128, n * 128);
        }
    }
    grid_bar(P.bar, ep);

    // ======== T-loop: 4 phases / step
    for (int t = 0; t < TT; ++t) {
        const int act = P.cnt[t];     // cached (post-inv, write-once)

        attn_job(P, bid & 255, bid >> 8, t, wred, es, alph);
        grid_bar(P.bar, ep);

        // G2 partials = awe @ Wih[:,1024:3072]^T (kz x4, K=512, 256 jobs)
        if (bid < 256) {
            const int kz = bid & 3, q = bid >> 2;
            const int n = q & 31, m = q >> 5;
            if (m * 128 < act) {
                f32x4 acc[4][4];
                #pragma unroll
                for (int i = 0; i < 4; ++i)
                    #pragma unroll
                    for (int jj = 0; jj < 4; ++jj) acc[i][jj] = (f32x4){0.f, 0.f, 0.f, 0.f};
                gemm_core<17, 0>(SH, P.aweb + kz * 512, 2048,
                                 P.Wihb + 1024 + kz * 512, 3072, 512,
                                 m * 128, n * 128, acc);
                // epilogue -> G2p (sc scalar f32)
                const int lane = tid & 63, w = tid >> 6;
                const int wr = w >> 1, wc = w & 1;
                float* Cz = P.G2p + (size_t)kz * (BB * 4096);
                #pragma unroll
                for (int mi = 0; mi < 4; ++mi) {
                    const int mbase = m * 128 + wr * 64 + mi * 16 + ((lane >> 4) << 2);
                    #pragma unroll
                    for (int nj = 0; nj < 4; ++nj) {
                        const int nn = n * 128 + wc * 64 + nj * 16 + (lane & 15);
                        #pragma unroll
                        for (int r = 0; r < 4; ++r)
                            st_f32_sc(&Cz[(size_t)(mbase + r) * 4096 + nn], acc[mi][nj][r]);
                    }
                }
            }
        }
        grid_bar(P.bar, ep);

        if (bid < 256) lstm_job(P, bid, t);
        grid_bar(P.bar, ep);

        // fused [Hcat(t+1) | preds(t)] = h @ Wbig^T + bcat (272 jobs)
        if (bid < 272) {
            const int n0 = ((bid >> 4) * 8 + (bid & 7)) * 128;
            const int m0 = ((bid >> 3) & 1) * 128;
            f32x4 acc[4][4];
            #pragma unroll
            for (int i = 0; i < 4; ++i)
                #pragma unroll
                for (int jj = 0; jj < 4; ++jj) acc[i][jj] = (f32x4){0.f, 0.f, 0.f, 0.f};
            const bool live = (m0 < act);
            if (live)
                gemm_core<17, 0>(SH, P.hb, 1024, P.Wbigb, 1024, 1024, m0, n0, acc);
            const int lane = tid & 63, w = tid >> 6;
            const int wr = w >> 1, wc = w & 1;
            float* C2 = P.outP + (size_t)t * VOCAB;
            #pragma unroll
            for (int mi = 0; mi < 4; ++mi) {
                const int mbase = m0 + wr * 64 + mi * 16 + ((lane >> 4) << 2);
                #pragma unroll
                for (int nj = 0; nj < 4; ++nj) {
                    const int n = n0 + wc * 64 + nj * 16 + (lane & 15);
                    if (n >= NBIG) continue;
                    const float bval = P.bcat[n];   // cached
                    #pragma unroll
                    for (int r = 0; r < 4; ++r) {
                        const int m = mbase + r;
                        const float v = acc[mi][nj][r] + bval;
                        if (n < NSPLIT) {
                            if (live) st_f32_sc(&P.Hcat[(size_t)m * 7168 + n], v);
                        } else {
                            C2[(size_t)m * (TT * VOCAB) + (n - NSPLIT)] = (m < act) ? v : 0.f;
                        }
                    }
                }
            }
        }
        grid_bar(P.bar, ep);
    }
}

// ---------------------------------------------------------------------------
extern "C" void kernel_launch(void* const* d_in, const int* in_sizes, int n_in,
                              void* d_out, int out_size, void* d_ws, size_t ws_size,
                              hipStream_t stream)
{
    MegaParams P;
    P.enc  = (const float*)d_in[0];
    P.objs = (const float*)d_in[1];
    P.caps = (const int*)d_in[2];
    P.clen = (const int*)d_in[3];
    P.emb  = (const float*)d_in[4];
    P.Wea  = (const float*)d_in[5];
    P.bea  = (const float*)d_in[6];
    P.Wda  = (const float*)d_in[7];
    P.bda  = (const float*)d_in[8];
    P.wfa  = (const float*)d_in[9];
    P.bfa  = (const float*)d_in[10];
    P.Wfb  = (const float*)d_in[11];
    P.bfb  = (const float*)d_in[12];
    P.Wih  = (const float*)d_in[13];
    P.Whh  = (const float*)d_in[14];
    P.bih  = (const float*)d_in[15];
    P.bhh  = (const float*)d_in[16];
    P.Wfc  = (const float*)d_in[17];
    P.bfc  = (const float*)d_in[18];

    P.outP     = (float*)d_out;
    P.out_caps = P.outP + (size_t)BB * TT * VOCAB;
    P.out_len  = P.out_caps + BB * TT;
    P.out_alph = P.out_len + BB;
    P.out_sind = P.out_alph + (size_t)BB * TT * NOBJ;

    char* wp = (char*)d_ws;
    auto alloc = [&](size_t bytes) -> void* {
        void* r = (void*)wp;
        wp += (bytes + 255) & ~(size_t)255;
        return r;
    };
    P.bar   = (int*)alloc(256);
    P.sidx  = (int*)alloc(BB * 4);
    P.slen  = (int*)alloc(BB * 4);
    P.cnt   = (int*)alloc(32 * 4);
    P.objsb = (u16*)alloc((size_t)BB * NOBJ * OBJD * 2);
    P.Wbigb = (u16*)alloc((size_t)NBIGP2 * 1024 * 2);
    P.bcat  = (float*)alloc(NBIGP2 * 4);
    P.Wihb  = (u16*)alloc((size_t)4096 * 3072 * 2);
    P.bsum  = (float*)alloc(4096 * 4);
    P.Weab  = (u16*)alloc((size_t)1024 * OBJD * 2);
    P.att1b = (u16*)alloc((size_t)BB * NOBJ * ATTD * 2);
    P.Xb    = (u16*)alloc((size_t)TT * BB * DECD * 2);
    P.Gxb   = (u16*)alloc((size_t)TT * BB * 4096 * 2);
    P.Hcat  = (float*)alloc((size_t)BB * 7168 * 4);
    P.aweb  = (u16*)alloc((size_t)BB * 2048 * 2);
    P.G2p   = (float*)alloc((size_t)4 * BB * 4096 * 4);
    P.c     = (float*)alloc((size_t)BB * DECD * 4);
    P.hb    = (u16*)alloc((size_t)BB * DECD * 2);
    (void)ws_size; (void)in_sizes; (void)n_in; (void)out_size;

    hipMemsetAsync(P.bar, 0, 256, stream);
    mega<<<NGRID, 256, 0, stream>>>(P);
}

// Round 8
// 3567.670 us; speedup vs baseline: 1.2464x; 1.2464x over previous
//
#include <hip/hip_runtime.h>
#include <hip/hip_bf16.h>
#include <cstdint>
#include <cstddef>

#define BB 256
#define TT 20
#define NOBJ 36
#define OBJD 2048
#define ATTD 1024
#define DECD 1024
#define VOCAB 10000
#define NBIG   17168   // 7168 (Wda|Wfb|Whh-interleaved) + 10000 (Wfc)
#define NBIGP2 17408   // 136 panels of 128
#define NSPLIT 7168
#define NGRID  512     // persistent blocks (2 per CU guaranteed)

typedef unsigned short u16;
typedef __attribute__((ext_vector_type(8))) short short8v;
typedef __attribute__((ext_vector_type(4))) float f32x4;
typedef __attribute__((ext_vector_type(2))) unsigned int u32x2;

__device__ inline u16 f2bf(float f) {
    __hip_bfloat16 h = __float2bfloat16(f);
    return *reinterpret_cast<u16*>(&h);
}
__device__ inline float bu(u16 u) {
    union { unsigned int i; float f; } x;
    x.i = ((unsigned int)u) << 16;
    return x.f;
}
__device__ inline float sigf(float x) { return 1.f / (1.f + expf(-x)); }

// ---- explicit device-coherent (sc0|sc1 = bypass L1+L2, at MALL) helpers ----
__device__ inline void st_u16_sc(u16* p, u16 v) {
    unsigned vv = v;
    asm volatile("global_store_short %0, %1, off sc0 sc1" :: "v"(p), "v"(vv) : "memory");
}
__device__ inline void st_u32_sc(void* p, unsigned v) {
    asm volatile("global_store_dword %0, %1, off sc0 sc1" :: "v"(p), "v"(v) : "memory");
}
__device__ inline void st_f32_sc(float* p, float v) {
    asm volatile("global_store_dword %0, %1, off sc0 sc1" :: "v"(p), "v"(v) : "memory");
}
__device__ inline void st_u64_sc(void* p, u32x2 v) {
    asm volatile("global_store_dwordx2 %0, %1, off sc0 sc1" :: "v"(p), "v"(v) : "memory");
}
__device__ inline void st_f4_sc(float* p, f32x4 v) {
    asm volatile("global_store_dwordx4 %0, %1, off sc0 sc1" :: "v"(p), "v"(v) : "memory");
}
__device__ inline unsigned ld_u32_sc(const int* p) {
    unsigned r;
    asm volatile("global_load_dword %0, %1, off sc0 sc1\n\ts_waitcnt vmcnt(0)"
                 : "=v"(r) : "v"(p) : "memory");
    return r;
}
__device__ inline f32x4 ld_f4_sc(const float* p) {
    f32x4 r;
    asm volatile("global_load_dwordx4 %0, %1, off sc0 sc1\n\ts_waitcnt vmcnt(0)"
                 : "=v"(r) : "v"(p) : "memory");
    return r;
}
__device__ inline void ld2_f4_sc(const float* p0, const float* p1, f32x4& a, f32x4& b) {
    asm volatile("global_load_dwordx4 %0, %2, off sc0 sc1\n\t"
                 "global_load_dwordx4 %1, %3, off sc0 sc1\n\t"
                 "s_waitcnt vmcnt(0)"
                 : "=&v"(a), "=&v"(b) : "v"(p0), "v"(p1) : "memory");
}

// async global->LDS, 16B/lane. AUX: 0 = cached, 17 = SC0|SC1 (device-coherent)
template<int AUX>
__device__ inline void gload16(const u16* g, u16* l) {
    __builtin_amdgcn_global_load_lds(
        (const __attribute__((address_space(1))) unsigned int*)g,
        (__attribute__((address_space(3))) unsigned int*)l, 16, 0, AUX);
}

struct MegaParams {
    const float* enc; const float* objs; const int* caps; const int* clen;
    const float* emb;
    const float* Wea; const float* bea; const float* Wda; const float* bda;
    const float* wfa; const float* bfa; const float* Wfb; const float* bfb;
    const float* Wih; const float* Whh; const float* bih; const float* bhh;
    const float* Wfc; const float* bfc;
    float* outP; float* out_caps; float* out_len; float* out_alph; float* out_sind;
    int* bar; int* sidx; int* slen; int* cnt;
    u16* objsb; u16* Wbigb; float* bcat; u16* Wihb; float* bsum; u16* Weab;
    u16* att1b; u16* Xb; u16* Gxb; float* Hcat; u16* aweb;
    float* c; u16* hb;
};

// ---------------------------------------------------------------------------
// Flag-array grid barrier: arrival = parallel sc-stores (no RMW contention);
// block 0 gathers 512 flags with 256 threads; release = one sc flag; spinners
// poll with sc loads (reads don't serialize at MALL). Bounded-spin insurance.
// ---------------------------------------------------------------------------
__device__ inline void grid_bar(int* arr, int* rel, int& ep) {
    __syncthreads();
    ++ep;
    const int tid = threadIdx.x;
    if (tid == 0) st_u32_sc(&arr[blockIdx.x], (unsigned)ep);
    if (blockIdx.x == 0) {
        int a0 = 0, a1 = 0, guard = 0;
        while ((a0 < ep || a1 < ep) && guard < (1 << 20)) {
            if (a0 < ep) a0 = (int)ld_u32_sc(&arr[tid * 2]);
            if (a1 < ep) a1 = (int)ld_u32_sc(&arr[tid * 2 + 1]);
            ++guard;
            if (a0 < ep || a1 < ep) __builtin_amdgcn_s_sleep(2);
        }
        __syncthreads();
        if (tid == 0) st_u32_sc(rel, (unsigned)ep);
    } else {
        if (tid == 0) {
            int guard = 0;
            while ((int)ld_u32_sc(rel) < ep && ++guard < (1 << 20))
                __builtin_amdgcn_s_sleep(2);
        }
        __syncthreads();
    }
}

// ---------------------------------------------------------------------------
// 128x128xK GEMM core. A 6-deep / B 3-deep pipeline, uniform vmcnt(10),
// clamped tail prefetch. LDS 72KB. Source-pre-swizzled global_load_lds +
// swizzled ds_read_b128. K % 32 == 0, K/32 >= 6.
// ---------------------------------------------------------------------------
template<int AUXA, int AUXB>
__device__ void gemm_core(u16* SH,
    const u16* __restrict__ A, int lda,
    const u16* __restrict__ B, int ldb,
    int K, int m0, int n0, f32x4 acc[4][4])
{
    u16* AsB = SH;                 // 6 slots x 4096 u16
    u16* BsB = SH + 6 * 4096;      // 3 slots x 4096 u16
    const int tid = threadIdx.x;
    const int lane = tid & 63;
    const int w = tid >> 6;
    const int wr = w >> 1, wc = w & 1;

    const int r0 = (w * 2 + 0) * 16 + (lane >> 2);
    const int r1 = (w * 2 + 1) * 16 + (lane >> 2);
    const int s0 = (lane & 3) ^ ((r0 >> 1) & 3);
    const int s1 = (lane & 3) ^ ((r1 >> 1) & 3);
    const u16* gA0 = A + (size_t)(m0 + r0) * lda + s0 * 8;
    const u16* gA1 = A + (size_t)(m0 + r1) * lda + s1 * 8;
    const u16* gB0 = B + (size_t)(n0 + r0) * ldb + s0 * 8;
    const u16* gB1 = B + (size_t)(n0 + r1) * ldb + s1 * 8;
    const int la0 = (w * 2 + 0) * 512;
    const int la1 = (w * 2 + 1) * 512;

    int ia[4], ib[4];
    #pragma unroll
    for (int mi = 0; mi < 4; ++mi) {
        const int r = wr * 64 + mi * 16 + (lane & 15);
        ia[mi] = r * 32 + (((lane >> 4) ^ ((r >> 1) & 3)) << 3);
    }
    #pragma unroll
    for (int nj = 0; nj < 4; ++nj) {
        const int r = wc * 64 + nj * 16 + (lane & 15);
        ib[nj] = r * 32 + (((lane >> 4) ^ ((r >> 1) & 3)) << 3);
    }

    const int nk = K >> 5;
    gload16<AUXA>(gA0 + 0 * 32, AsB + 0 * 4096 + la0);
    gload16<AUXA>(gA1 + 0 * 32, AsB + 0 * 4096 + la1);
    gload16<AUXA>(gA0 + 1 * 32, AsB + 1 * 4096 + la0);
    gload16<AUXA>(gA1 + 1 * 32, AsB + 1 * 4096 + la1);
    gload16<AUXA>(gA0 + 2 * 32, AsB + 2 * 4096 + la0);
    gload16<AUXA>(gA1 + 2 * 32, AsB + 2 * 4096 + la1);
    gload16<AUXB>(gB0 + 0 * 32, BsB + 0 * 4096 + la0);
    gload16<AUXB>(gB1 + 0 * 32, BsB + 0 * 4096 + la1);
    gload16<AUXA>(gA0 + 3 * 32, AsB + 3 * 4096 + la0);
    gload16<AUXA>(gA1 + 3 * 32, AsB + 3 * 4096 + la1);
    gload16<AUXB>(gB0 + 1 * 32, BsB + 1 * 4096 + la0);
    gload16<AUXB>(gB1 + 1 * 32, BsB + 1 * 4096 + la1);
    gload16<AUXA>(gA0 + 4 * 32, AsB + 4 * 4096 + la0);
    gload16<AUXA>(gA1 + 4 * 32, AsB + 4 * 4096 + la1);
    gload16<AUXB>(gB0 + 2 * 32, BsB + 2 * 4096 + la0);
    gload16<AUXB>(gB1 + 2 * 32, BsB + 2 * 4096 + la1);
    gload16<AUXA>(gA0 + 5 * 32, AsB + 5 * 4096 + la0);
    gload16<AUXA>(gA1 + 5 * 32, AsB + 5 * 4096 + la1);

    int sa = 0, sb = 0;
    for (int it = 0; it < nk; ++it) {
        asm volatile("s_waitcnt vmcnt(10)" ::: "memory");
        __builtin_amdgcn_s_barrier();
        const u16* Asc = AsB + sa * 4096;
        const u16* Bsc = BsB + sb * 4096;
        short8v av[4], bv[4];
        #pragma unroll
        for (int mi = 0; mi < 4; ++mi) av[mi] = *(const short8v*)&Asc[ia[mi]];
        #pragma unroll
        for (int nj = 0; nj < 4; ++nj) bv[nj] = *(const short8v*)&Bsc[ib[nj]];
        __builtin_amdgcn_s_setprio(1);
        #pragma unroll
        for (int mi = 0; mi < 4; ++mi)
            #pragma unroll
            for (int nj = 0; nj < 4; ++nj)
                acc[mi][nj] = __builtin_amdgcn_mfma_f32_16x16x32_bf16(
                    av[mi], bv[nj], acc[mi][nj], 0, 0, 0);
        __builtin_amdgcn_s_setprio(0);
        __builtin_amdgcn_s_barrier();
        {
            const int bt = (it + 3 < nk) ? (it + 3) : (nk - 1);
            const int at = (it + 6 < nk) ? (it + 6) : (nk - 1);
            gload16<AUXB>(gB0 + bt * 32, BsB + sb * 4096 + la0);
            gload16<AUXB>(gB1 + bt * 32, BsB + sb * 4096 + la1);
            gload16<AUXA>(gA0 + at * 32, AsB + sa * 4096 + la0);
            gload16<AUXA>(gA1 + at * 32, AsB + sa * 4096 + la1);
        }
        sa = (sa == 5) ? 0 : sa + 1;
        sb = (sb == 2) ? 0 : sb + 1;
    }
    asm volatile("s_waitcnt vmcnt(0)" ::: "memory");
    __builtin_amdgcn_s_barrier();
}

// Setup epilogue: bf16 C via sc stores (write-once, cached-read later)
__device__ void epi_bf16(f32x4 acc[4][4], u16* Cb, int ldc,
                         const float* bias, int m0, int n0)
{
    const int lane = threadIdx.x & 63;
    const int w = threadIdx.x >> 6;
    const int wr = w >> 1, wc = w & 1;
    #pragma unroll
    for (int mi = 0; mi < 4; ++mi) {
        const int mbase = m0 + wr * 64 + mi * 16 + ((lane >> 4) << 2);
        #pragma unroll
        for (int nj = 0; nj < 4; ++nj) {
            const int n = n0 + wc * 64 + nj * 16 + (lane & 15);
            const float bval = bias ? bias[n] : 0.f;
            #pragma unroll
            for (int r = 0; r < 4; ++r)
                st_u16_sc(&Cb[(size_t)(mbase + r) * ldc + n], f2bf(acc[mi][nj][r] + bval));
        }
    }
}

// ---------------------------------------------------------------------------
// Attention (z-split, XCD-paired): b, z derived so both z of a row share an
// XCD (att1 L2 reuse). att1b/objsb cached; Hcat sc; aweb written sc.
// ---------------------------------------------------------------------------
__device__ void attn_job(const MegaParams& P, int b, int z, int t,
                         float (*wred)[40], float* es, float* alph)
{
    const int tid = threadIdx.x;
    if (t >= P.slen[b]) {
        if (z == 0 && tid < NOBJ)
            P.out_alph[((size_t)b * TT + t) * NOBJ + tid] = 0.f;
        return;
    }
    const int lane = tid & 63, w = tid >> 6;
    const float* hrow = P.Hcat + (size_t)b * 7168;
    f32x4 h4, g0;
    ld2_f4_sc(hrow + tid * 4, hrow + 1024 + z * 1024 + tid * 4, h4, g0);
    const f32x4 w4 = *((const f32x4*)P.wfa + tid);
    const u16* a1base = P.att1b + (size_t)b * NOBJ * ATTD;

    float ep[NOBJ];
    #pragma unroll
    for (int n = 0; n < NOBJ; ++n) {
        ushort4 a4 = ((const ushort4*)(a1base + (size_t)n * ATTD))[tid];
        const float v0 = fmaxf(bu(a4.x) + h4[0], 0.f);
        const float v1 = fmaxf(bu(a4.y) + h4[1], 0.f);
        const float v2 = fmaxf(bu(a4.z) + h4[2], 0.f);
        const float v3 = fmaxf(bu(a4.w) + h4[3], 0.f);
        ep[n] = v0 * w4[0] + v1 * w4[1] + v2 * w4[2] + v3 * w4[3];
    }
    #pragma unroll
    for (int n = 0; n < NOBJ; ++n) {
        float p = ep[n];
        #pragma unroll
        for (int off = 32; off > 0; off >>= 1) p += __shfl_down(p, off, 64);
        if (lane == 0) wred[w][n] = p;
    }
    __syncthreads();
    if (tid < NOBJ)
        es[tid] = wred[0][tid] + wred[1][tid] + wred[2][tid] + wred[3][tid] + P.bfa[0];
    __syncthreads();
    if (tid < 64) {
        float mv = (tid < NOBJ) ? es[tid] : -1e30f;
        #pragma unroll
        for (int off = 32; off > 0; off >>= 1) mv = fmaxf(mv, __shfl_xor(mv, off, 64));
        float e = (tid < NOBJ) ? expf(es[tid] - mv) : 0.f;
        float s = e;
        #pragma unroll
        for (int off = 32; off > 0; off >>= 1) s += __shfl_xor(s, off, 64);
        if (tid < NOBJ) alph[tid] = e / s;
    }
    __syncthreads();
    if (z == 0 && tid < NOBJ)
        P.out_alph[((size_t)b * TT + t) * NOBJ + tid] = alph[tid];

    float acc[4] = {0.f, 0.f, 0.f, 0.f};
    const u16* ob = P.objsb + (size_t)b * NOBJ * OBJD + z * 1024 + tid * 4;
    #pragma unroll 4
    for (int n = 0; n < NOBJ; ++n) {
        const ushort4 ov = *(const ushort4*)(ob + (size_t)n * OBJD);
        const float al = alph[n];
        acc[0] = fmaf(al, bu(ov.x), acc[0]);
        acc[1] = fmaf(al, bu(ov.y), acc[1]);
        acc[2] = fmaf(al, bu(ov.z), acc[2]);
        acc[3] = fmaf(al, bu(ov.w), acc[3]);
    }
    ushort4 st;
    st.x = f2bf(acc[0] * sigf(g0[0]));
    st.y = f2bf(acc[1] * sigf(g0[1]));
    st.z = f2bf(acc[2] * sigf(g0[2]));
    st.w = f2bf(acc[3] * sigf(g0[3]));
    union { ushort4 s; u32x2 u; } cvt; cvt.s = st;
    st_u64_sc(&P.aweb[(size_t)b * 2048 + z * 1024 + tid * 4], cvt.u);
}

// ---------------------------------------------------------------------------
// G2 GEMM + fused LSTM (gate-interleaved: col n = 4d+q). Block bid<64 owns
// tile (m=bid>>5, n=bid&31) -> dims [32n, 32n+32) of rows in its m-tile;
// c ownership fixed across t (block-private cached). hb written sc.
// ---------------------------------------------------------------------------
__device__ void g2l_job(const MegaParams& P, u16* SH, int t, int act)
{
    const int bid = blockIdx.x, tid = threadIdx.x;
    const int m0 = (bid >> 5) * 128, n0 = (bid & 31) * 128;
    if (m0 >= act) return;

    f32x4 acc[4][4];
    #pragma unroll
    for (int i = 0; i < 4; ++i)
        #pragma unroll
        for (int j = 0; j < 4; ++j) acc[i][j] = (f32x4){0.f, 0.f, 0.f, 0.f};
    gemm_core<17, 0>(SH, P.aweb, 2048, P.Wihb + 1024, 3072, 2048, m0, n0, acc);

    const int lane = tid & 63, w = tid >> 6;
    const int wr = w >> 1, wc = w & 1;
    float* patch = (float*)SH;   // 64 x 128 f32 = 32KB (safe: gemm_core done)
    #pragma unroll
    for (int half = 0; half < 2; ++half) {
        __syncthreads();
        if (wr == half) {
            #pragma unroll
            for (int mi = 0; mi < 4; ++mi) {
                const int rbase = mi * 16 + ((lane >> 4) << 2);
                #pragma unroll
                for (int nj = 0; nj < 4; ++nj) {
                    const int col = wc * 64 + nj * 16 + (lane & 15);
                    #pragma unroll
                    for (int r = 0; r < 4; ++r)
                        patch[(rbase + r) * 128 + col] = acc[mi][nj][r];
                }
            }
        }
        __syncthreads();
        const int h0 = half * 64;
        #pragma unroll
        for (int p8 = 0; p8 < 8; ++p8) {
            const int idx = p8 * 256 + tid;
            const int row = idx >> 5, dl = idx & 31;
            const int b = m0 + h0 + row;
            if (b >= act) continue;
            const int d = (n0 >> 2) + dl;
            const float* pr = patch + row * 128 + dl * 4;
            float gi = pr[0], gf = pr[1], gg = pr[2], go = pr[3];
            const ushort4 xv = *(const ushort4*)(P.Gxb + ((size_t)(t * BB + b)) * 4096 + n0 + dl * 4);
            gi += bu(xv.x); gf += bu(xv.y); gg += bu(xv.z); go += bu(xv.w);
            const f32x4 hv = ld_f4_sc(P.Hcat + (size_t)b * 7168 + 3072 + n0 + dl * 4);
            gi += hv[0]; gf += hv[1]; gg += hv[2]; go += hv[3];
            float* cp = P.c + (size_t)b * 1024 + d;
            const float cn = sigf(gf) * cp[0] + sigf(gi) * tanhf(gg);
            const float hn = sigf(go) * tanhf(cn);
            cp[0] = cn;                                   // block-private
            st_u16_sc(&P.hb[(size_t)b * 1024 + d], f2bf(hn));
        }
    }
}

// ---------------------------------------------------------------------------
// Persistent megakernel.
// ---------------------------------------------------------------------------
__global__ __launch_bounds__(256, 2) void mega(MegaParams P)
{
    __shared__ __align__(16) u16 SH[9 * 4096];   // 72KB
    __shared__ float wred[4][40];
    __shared__ float es[40];
    __shared__ float alph[40];
    __shared__ int Ls[BB];
    __shared__ int SLs[BB];
    const int bid = blockIdx.x;
    const int tid = threadIdx.x;
    int ep = 0;
    int* rel = P.bar;
    int* arr = P.bar + 64;

    // ======== S0: flush pre-kernel dirty L2 lines, then sync
    __builtin_amdgcn_fence(__ATOMIC_RELEASE, "agent");
    grid_bar(arr, rel, ep);

    // ======== S1a: sort (block 0) + weight conversions (sc stores) + zero c
    if (bid == 0) {
        const int li = P.clen[tid];
        Ls[tid] = li;
        __syncthreads();
        int r = 0;
        for (int j = 0; j < BB; ++j) {
            const int lj = Ls[j];
            if (lj > li || (lj == li && j < tid)) r++;
        }
        st_u32_sc(&P.sidx[r], (unsigned)tid);
        st_u32_sc(&P.slen[r], (unsigned)li);
        SLs[r] = li;
        st_f32_sc(&P.out_sind[r], (float)tid);
        st_f32_sc(&P.out_len[r], (float)li);
        __syncthreads();
        if (tid < TT) {
            int cc = 0;
            for (int b2 = 0; b2 < BB; ++b2) cc += (SLs[b2] > tid);
            st_u32_sc(&P.cnt[tid], (unsigned)cc);
        }
    }
    for (int n = bid; n < NBIGP2; n += NGRID) {
        const float* src = nullptr;
        float bbv = 0.f;
        if (n < 1024)      { src = P.Wda + (size_t)n * 1024;          bbv = P.bda[n]; }
        else if (n < 3072) { src = P.Wfb + (size_t)(n - 1024) * 1024; bbv = P.bfb[n - 1024]; }
        else if (n < 7168) {
            const int loc = n - 3072, q = loc & 3, d = loc >> 2;
            src = P.Whh + ((size_t)q * 1024 + d) * 1024;
        }
        else if (n < NBIG) { src = P.Wfc + (size_t)(n - 7168) * 1024; bbv = P.bfc[n - 7168]; }
        ushort4 s4;
        if (src) {
            float4 v = ((const float4*)src)[tid];
            s4.x = f2bf(v.x); s4.y = f2bf(v.y); s4.z = f2bf(v.z); s4.w = f2bf(v.w);
        } else { s4.x = s4.y = s4.z = s4.w = 0; }
        union { ushort4 s; u32x2 u; } cvt; cvt.s = s4;
        st_u64_sc(&P.Wbigb[(size_t)n * 1024 + tid * 4], cvt.u);
        if (tid == 0) st_f32_sc(&P.bcat[n], bbv);
    }
    for (int n = bid; n < 4096; n += NGRID) {
        const int q = n & 3, d = n >> 2;
        const float* src = P.Wih + ((size_t)q * 1024 + d) * 3072;
        u16* dst = P.Wihb + (size_t)n * 3072;
        #pragma unroll
        for (int j = 0; j < 3; ++j) {
            float4 v = ((const float4*)src)[tid + 256 * j];
            ushort4 s4;
            s4.x = f2bf(v.x); s4.y = f2bf(v.y); s4.z = f2bf(v.z); s4.w = f2bf(v.w);
            union { ushort4 s; u32x2 u; } cvt; cvt.s = s4;
            st_u64_sc(&dst[(tid + 256 * j) * 4], cvt.u);
        }
        if (tid == 0) st_f32_sc(&P.bsum[n], P.bih[q * 1024 + d] + P.bhh[q * 1024 + d]);
    }
    for (int n = bid; n < 1024; n += NGRID) {
        const float* src = P.Wea + (size_t)n * OBJD;
        u16* dst = P.Weab + (size_t)n * OBJD;
        #pragma unroll
        for (int j = 0; j < 2; ++j) {
            float4 v = ((const float4*)src)[tid + 256 * j];
            ushort4 s4;
            s4.x = f2bf(v.x); s4.y = f2bf(v.y); s4.z = f2bf(v.z); s4.w = f2bf(v.w);
            union { ushort4 s; u32x2 u; } cvt; cvt.s = s4;
            st_u64_sc(&dst[(tid + 256 * j) * 4], cvt.u);
        }
    }
    if (bid < BB)
        st_f4_sc(P.c + (size_t)bid * 1024 + tid * 4, (f32x4){0.f, 0.f, 0.f, 0.f});
    grid_bar(arr, rel, ep);

    // ======== S1b: sorted gathers + Hcat(0)
    for (int row = bid; row < BB * NOBJ; row += NGRID) {
        const int b = row / NOBJ, n = row - b * NOBJ;
        const int sb = (int)ld_u32_sc(&P.sidx[b]);
        const float* src = P.objs + ((size_t)sb * NOBJ + n) * OBJD;
        u16* dst = P.objsb + (size_t)row * OBJD;
        #pragma unroll
        for (int j = 0; j < 2; ++j) {
            float4 v = ((const float4*)src)[tid + 256 * j];
            ushort4 s4;
            s4.x = f2bf(v.x); s4.y = f2bf(v.y); s4.z = f2bf(v.z); s4.w = f2bf(v.w);
            union { ushort4 s; u32x2 u; } cvt; cvt.s = s4;
            st_u64_sc(&dst[(tid + 256 * j) * 4], cvt.u);
        }
    }
    for (int blk = bid; blk < TT * BB; blk += NGRID) {
        const int t = blk >> 8, b = blk & 255;
        const int sb = (int)ld_u32_sc(&P.sidx[b]);
        const float* src = (t == 0) ? (P.enc + (size_t)sb * DECD)
                                    : (P.emb + (size_t)P.caps[sb * TT + (t - 1)] * DECD);
        float4 v = ((const float4*)src)[tid];
        ushort4 s4;
        s4.x = f2bf(v.x); s4.y = f2bf(v.y); s4.z = f2bf(v.z); s4.w = f2bf(v.w);
        union { ushort4 s; u32x2 u; } cvt; cvt.s = s4;
        st_u64_sc(&P.Xb[(size_t)blk * DECD + tid * 4], cvt.u);
    }
    if (bid == 1) {
        for (int i = tid; i < BB * TT; i += 256) {
            const int p = i / TT, t = i % TT;
            const int sb = (int)ld_u32_sc(&P.sidx[p]);
            st_f32_sc(&P.out_caps[i], (float)P.caps[sb * TT + t]);
        }
    }
    if (bid < BB) {
        float* dst = P.Hcat + (size_t)bid * 7168;
        for (int i = tid; i < 1792; i += 256)
            st_f4_sc(dst + i * 4, ld_f4_sc(P.bcat + i * 4));
    }
    grid_bar(arr, rel, ep);

    // ======== one-time L2 invalidate; thereafter write-once data reads cached
    __builtin_amdgcn_fence(__ATOMIC_ACQUIRE, "agent");

    // ======== S2: att1 (576 jobs) + Gx (1280 jobs)
    for (int j = bid; j < 576 + 1280; j += NGRID) {
        f32x4 acc[4][4];
        #pragma unroll
        for (int i = 0; i < 4; ++i)
            #pragma unroll
            for (int jj = 0; jj < 4; ++jj) acc[i][jj] = (f32x4){0.f, 0.f, 0.f, 0.f};
        if (j < 576) {
            const int n = j / 72, m = j % 72;
            gemm_core<0, 0>(SH, P.objsb, OBJD, P.Weab, OBJD, OBJD, m * 128, n * 128, acc);
            epi_bf16(acc, P.att1b, ATTD, P.bea, m * 128, n * 128);
        } else {
            const int j2 = j - 576;
            const int n = j2 / 40, m = j2 % 40;
            gemm_core<0, 0>(SH, P.Xb, DECD, P.Wihb, 3072, DECD, m * 128, n * 128, acc);
            epi_bf16(acc, P.Gxb, 4096, P.bsum, m * 128, n * 128);
        }
    }
    grid_bar(arr, rel, ep);

    // ======== T-loop: 3 phases / step
    for (int t = 0; t < TT; ++t) {
        const int act = P.cnt[t];

        attn_job(P, (bid & 7) | ((bid >> 4) << 3), (bid >> 3) & 1, t, wred, es, alph);
        grid_bar(arr, rel, ep);

        if (bid < 64) g2l_job(P, SH, t, act);
        grid_bar(arr, rel, ep);

        if (bid < 272) {
            const int n0 = ((bid >> 4) * 8 + (bid & 7)) * 128;
            const int m0 = ((bid >> 3) & 1) * 128;
            f32x4 acc[4][4];
            #pragma unroll
            for (int i = 0; i < 4; ++i)
                #pragma unroll
                for (int jj = 0; jj < 4; ++jj) acc[i][jj] = (f32x4){0.f, 0.f, 0.f, 0.f};
            const bool live = (m0 < act);
            if (live)
                gemm_core<17, 0>(SH, P.hb, 1024, P.Wbigb, 1024, 1024, m0, n0, acc);
            const int lane = tid & 63, w = tid >> 6;
            const int wr = w >> 1, wc = w & 1;
            float* C2 = P.outP + (size_t)t * VOCAB;
            #pragma unroll
            for (int mi = 0; mi < 4; ++mi) {
                const int mbase = m0 + wr * 64 + mi * 16 + ((lane >> 4) << 2);
                #pragma unroll
                for (int nj = 0; nj < 4; ++nj) {
                    const int n = n0 + wc * 64 + nj * 16 + (lane & 15);
                    if (n >= NBIG) continue;
                    const float bval = P.bcat[n];
                    #pragma unroll
                    for (int r = 0; r < 4; ++r) {
                        const int m = mbase + r;
                        const float v = acc[mi][nj][r] + bval;
                        if (n < NSPLIT) {
                            if (live) st_f32_sc(&P.Hcat[(size_t)m * 7168 + n], v);
                        } else {
                            C2[(size_t)m * (TT * VOCAB) + (n - NSPLIT)] = (m < act) ? v : 0.f;
                        }
                    }
                }
            }
        }
        grid_bar(arr, rel, ep);
    }
}

// ---------------------------------------------------------------------------
extern "C" void kernel_launch(void* const* d_in, const int* in_sizes, int n_in,
                              void* d_out, int out_size, void* d_ws, size_t ws_size,
                              hipStream_t stream)
{
    MegaParams P;
    P.enc  = (const float*)d_in[0];
    P.objs = (const float*)d_in[1];
    P.caps = (const int*)d_in[2];
    P.clen = (const int*)d_in[3];
    P.emb  = (const float*)d_in[4];
    P.Wea  = (const float*)d_in[5];
    P.bea  = (const float*)d_in[6];
    P.Wda  = (const float*)d_in[7];
    P.bda  = (const float*)d_in[8];
    P.wfa  = (const float*)d_in[9];
    P.bfa  = (const float*)d_in[10];
    P.Wfb  = (const float*)d_in[11];
    P.bfb  = (const float*)d_in[12];
    P.Wih  = (const float*)d_in[13];
    P.Whh  = (const float*)d_in[14];
    P.bih  = (const float*)d_in[15];
    P.bhh  = (const float*)d_in[16];
    P.Wfc  = (const float*)d_in[17];
    P.bfc  = (const float*)d_in[18];

    P.outP     = (float*)d_out;
    P.out_caps = P.outP + (size_t)BB * TT * VOCAB;
    P.out_len  = P.out_caps + BB * TT;
    P.out_alph = P.out_len + BB;
    P.out_sind = P.out_alph + (size_t)BB * TT * NOBJ;

    char* wp = (char*)d_ws;
    auto alloc = [&](size_t bytes) -> void* {
        void* r = (void*)wp;
        wp += (bytes + 255) & ~(size_t)255;
        return r;
    };
    P.bar   = (int*)alloc(4096);
    P.sidx  = (int*)alloc(BB * 4);
    P.slen  = (int*)alloc(BB * 4);
    P.cnt   = (int*)alloc(32 * 4);
    P.objsb = (u16*)alloc((size_t)BB * NOBJ * OBJD * 2);
    P.Wbigb = (u16*)alloc((size_t)NBIGP2 * 1024 * 2);
    P.bcat  = (float*)alloc(NBIGP2 * 4);
    P.Wihb  = (u16*)alloc((size_t)4096 * 3072 * 2);
    P.bsum  = (float*)alloc(4096 * 4);
    P.Weab  = (u16*)alloc((size_t)1024 * OBJD * 2);
    P.att1b = (u16*)alloc((size_t)BB * NOBJ * ATTD * 2);
    P.Xb    = (u16*)alloc((size_t)TT * BB * DECD * 2);
    P.Gxb   = (u16*)alloc((size_t)TT * BB * 4096 * 2);
    P.Hcat  = (float*)alloc((size_t)BB * 7168 * 4);
    P.aweb  = (u16*)alloc((size_t)BB * 2048 * 2);
    P.c     = (float*)alloc((size_t)BB * DECD * 4);
    P.hb    = (u16*)alloc((size_t)BB * DECD * 2);
    (void)ws_size; (void)in_sizes; (void)n_in; (void)out_size;

    hipMemsetAsync(P.bar, 0, 4096, stream);
    mega<<<NGRID, 256, 0, stream>>>(P);
}

// Round 9
// 1727.756 us; speedup vs baseline: 2.5737x; 2.0649x over previous
//
#include <hip/hip_runtime.h>
#include <hip/hip_bf16.h>
#include <cstdint>
#include <cstddef>

#define BB 256
#define TT 20
#define NOBJ 36
#define OBJD 2048
#define ATTD 1024
#define DECD 1024
#define VOCAB 10000
#define NHC   7168     // Hcat width: 1024 (att2) + 2048 (gate) + 4096 (Whh gates, interleaved)
#define VOCP  10112    // vocab padded to 79 tiles of 128

typedef unsigned short u16;
typedef __attribute__((ext_vector_type(8))) short short8v;
typedef __attribute__((ext_vector_type(4))) float f32x4;

__device__ inline u16 f2bf(float f) {
    __hip_bfloat16 h = __float2bfloat16(f);
    return *reinterpret_cast<u16*>(&h);
}
__device__ inline float bu(u16 u) {
    union { unsigned int i; float f; } x;
    x.i = ((unsigned int)u) << 16;
    return x.f;
}
__device__ inline float sigf(float x) { return 1.f / (1.f + expf(-x)); }

// async global->LDS, 16B per lane (wave-uniform LDS base + lane*16)
__device__ inline void gload16(const u16* g, u16* l) {
    __builtin_amdgcn_global_load_lds(
        (const __attribute__((address_space(1))) unsigned int*)g,
        (__attribute__((address_space(3))) unsigned int*)l, 16, 0, 0);
}

// ---------------------------------------------------------------------------
// Sort: stable descending argsort of lengths (O(B^2), one block)
// ---------------------------------------------------------------------------
__global__ __launch_bounds__(256) void sort_kernel(
    const int* __restrict__ lens, int* __restrict__ sidx, int* __restrict__ slen,
    int* __restrict__ cnt, float* __restrict__ out_len, float* __restrict__ out_sind)
{
    __shared__ int L[BB];
    __shared__ int SL[BB];
    const int i = threadIdx.x;
    const int li = lens[i];
    L[i] = li;
    __syncthreads();
    int r = 0;
    for (int j = 0; j < BB; ++j) {
        const int lj = L[j];
        if (lj > li || (lj == li && j < i)) r++;
    }
    sidx[r] = i;
    slen[r] = li;
    SL[r] = li;
    out_sind[r] = (float)i;
    out_len[r]  = (float)li;
    __syncthreads();
    if (i < TT) {
        int cc = 0;
        for (int b = 0; b < BB; ++b) cc += (SL[b] > i);
        cnt[i] = cc;
    }
}

__global__ __launch_bounds__(256) void meta_kernel(
    const int* __restrict__ caps, const int* __restrict__ sidx,
    float* __restrict__ out_caps)
{
    const int idx = blockIdx.x * 256 + threadIdx.x;   // grid 20
    const int p = idx / TT, t = idx % TT;
    out_caps[idx] = (float)caps[sidx[p] * TT + t];
}

// gather objects in sorted order -> bf16 (9216 x 2048)
__global__ __launch_bounds__(256) void gather_objs(
    const float* __restrict__ objs, const int* __restrict__ sidx,
    u16* __restrict__ objsb)
{
    const int row = blockIdx.x;              // 0..9215
    const int b = row / NOBJ, n = row - b * NOBJ;
    const float* src = objs + ((size_t)sidx[b] * NOBJ + n) * OBJD;
    u16* dst = objsb + (size_t)row * OBJD;
    const int tid = threadIdx.x;
    #pragma unroll
    for (int j = 0; j < 2; ++j) {
        float4 v = ((const float4*)src)[tid + 256 * j];
        ushort4 s;
        s.x = f2bf(v.x); s.y = f2bf(v.y); s.z = f2bf(v.z); s.w = f2bf(v.w);
        ((ushort4*)dst)[tid + 256 * j] = s;
    }
}

// Whc = [Wda | Wfb | Whh gate-interleaved] (7168 x 1024) bf16 + bcat
__global__ __launch_bounds__(256) void convWhc(
    const float* __restrict__ Wda, const float* __restrict__ bda,
    const float* __restrict__ Wfb, const float* __restrict__ bfb,
    const float* __restrict__ Whh,
    u16* __restrict__ Wb, float* __restrict__ bcat)
{
    const int n = blockIdx.x;                // 0..7167
    const int tid = threadIdx.x;
    const float* src;
    float bb = 0.f;
    if (n < 1024)      { src = Wda + (size_t)n * 1024;          bb = bda[n]; }
    else if (n < 3072) { src = Wfb + (size_t)(n - 1024) * 1024; bb = bfb[n - 1024]; }
    else {
        const int loc = n - 3072, q = loc & 3, d = loc >> 2;   // col 3072+4d+q = h.Whh[q*1024+d]
        src = Whh + ((size_t)q * 1024 + d) * 1024;
    }
    float4 v = ((const float4*)src)[tid];
    ushort4 s;
    s.x = f2bf(v.x); s.y = f2bf(v.y); s.z = f2bf(v.z); s.w = f2bf(v.w);
    ((ushort4*)(Wb + (size_t)n * 1024))[tid] = s;
    if (tid == 0) bcat[n] = bb;
}

// Wfc padded (10112 x 1024) bf16
__global__ __launch_bounds__(256) void convWfc(
    const float* __restrict__ Wfc, u16* __restrict__ Wb)
{
    const int n = blockIdx.x;                // 0..10111
    const int tid = threadIdx.x;
    ushort4 s;
    if (n < VOCAB) {
        float4 v = ((const float4*)(Wfc + (size_t)n * 1024))[tid];
        s.x = f2bf(v.x); s.y = f2bf(v.y); s.z = f2bf(v.z); s.w = f2bf(v.w);
    } else { s.x = s.y = s.z = s.w = 0; }
    ((ushort4*)(Wb + (size_t)n * 1024))[tid] = s;
}

// Wih gate-interleaved rows (4096 x 3072) + bsum (interleaved b_ih + b_hh)
__global__ __launch_bounds__(256) void convWih(
    const float* __restrict__ Wih, const float* __restrict__ bih,
    const float* __restrict__ bhh, u16* __restrict__ Wb, float* __restrict__ bsum)
{
    const int n = blockIdx.x;                // 0..4095 ; n = 4d+q
    const int q = n & 3, d = n >> 2;
    const int tid = threadIdx.x;
    const float* src = Wih + ((size_t)q * 1024 + d) * 3072;
    u16* dst = Wb + (size_t)n * 3072;
    #pragma unroll
    for (int j = 0; j < 3; ++j) {
        float4 v = ((const float4*)src)[tid + 256 * j];
        ushort4 s;
        s.x = f2bf(v.x); s.y = f2bf(v.y); s.z = f2bf(v.z); s.w = f2bf(v.w);
        ((ushort4*)dst)[tid + 256 * j] = s;
    }
    if (tid == 0) bsum[n] = bih[q * 1024 + d] + bhh[q * 1024 + d];
}

// Wea (1024 x 2048) bf16
__global__ __launch_bounds__(256) void convWea(
    const float* __restrict__ Wea, u16* __restrict__ Wb)
{
    const int n = blockIdx.x;
    const int tid = threadIdx.x;
    const float* src = Wea + (size_t)n * OBJD;
    u16* dst = Wb + (size_t)n * OBJD;
    #pragma unroll
    for (int j = 0; j < 2; ++j) {
        float4 v = ((const float4*)src)[tid + 256 * j];
        ushort4 s;
        s.x = f2bf(v.x); s.y = f2bf(v.y); s.z = f2bf(v.z); s.w = f2bf(v.w);
        ((ushort4*)dst)[tid + 256 * j] = s;
    }
}

// X[t*B+b] bf16
__global__ __launch_bounds__(256) void embed_kernel(
    const float* __restrict__ enc, const int* __restrict__ caps,
    const float* __restrict__ emb, const int* __restrict__ sidx,
    u16* __restrict__ Xb)
{
    const int blk = blockIdx.x;     // grid T*B
    const int t = blk >> 8;
    const int b = blk & 255;
    const int sb = sidx[b];
    const float* src = (t == 0) ? (enc + (size_t)sb * DECD)
                                : (emb + (size_t)caps[sb * TT + (t - 1)] * DECD);
    const int tid = threadIdx.x;
    float4 v = ((const float4*)src)[tid];
    ushort4 s;
    s.x = f2bf(v.x); s.y = f2bf(v.y); s.z = f2bf(v.z); s.w = f2bf(v.w);
    ((ushort4*)(Xb + (size_t)blk * DECD))[tid] = s;
}

__global__ __launch_bounds__(256) void zero_c(float* __restrict__ c)
{
    ((float4*)c)[blockIdx.x * 256 + threadIdx.x] = make_float4(0.f, 0.f, 0.f, 0.f);
}

// Hcat(0) = broadcast bcat (h0 = 0)
__global__ __launch_bounds__(256) void hcat0_kernel(
    const float* __restrict__ bcat, float* __restrict__ Hcat)
{
    const int col4 = blockIdx.x * 256 + threadIdx.x;   // 0..1791
    const int m = blockIdx.y;
    ((float4*)(Hcat + (size_t)m * NHC))[col4] = ((const float4*)bcat)[col4];
}

// ---------------------------------------------------------------------------
// Shared 128x128xK GEMM core: 3-deep pipelined (counted vmcnt), source-pre-
// swizzled global_load_lds (LDS linear) + swizzled ds_read_b128. K%32==0.
// As = SH[0..12287], Bs = SH[12288..24575] (u16 units).
// ---------------------------------------------------------------------------
__device__ __forceinline__ void gemm_core(u16* SH,
    const u16* __restrict__ A, int lda,
    const u16* __restrict__ B, int ldb,
    int K, int m0, int n0, f32x4 acc[4][4])
{
    u16* AsB = SH;
    u16* BsB = SH + 12288;
    const int tid = threadIdx.x;
    const int lane = tid & 63;
    const int w = tid >> 6;
    const int wr = w >> 1, wc = w & 1;

    const int r0 = (w * 2 + 0) * 16 + (lane >> 2);
    const int r1 = (w * 2 + 1) * 16 + (lane >> 2);
    const int s0 = (lane & 3) ^ ((r0 >> 1) & 3);
    const int s1 = (lane & 3) ^ ((r1 >> 1) & 3);
    const u16* gA0 = A + (size_t)(m0 + r0) * lda + s0 * 8;
    const u16* gA1 = A + (size_t)(m0 + r1) * lda + s1 * 8;
    const u16* gB0 = B + (size_t)(n0 + r0) * ldb + s0 * 8;
    const u16* gB1 = B + (size_t)(n0 + r1) * ldb + s1 * 8;
    const int la0 = (w * 2 + 0) * 512;
    const int la1 = (w * 2 + 1) * 512;

    int ia[4], ib[4];
    #pragma unroll
    for (int mi = 0; mi < 4; ++mi) {
        const int r = wr * 64 + mi * 16 + (lane & 15);
        ia[mi] = r * 32 + (((lane >> 4) ^ ((r >> 1) & 3)) << 3);
    }
    #pragma unroll
    for (int nj = 0; nj < 4; ++nj) {
        const int r = wc * 64 + nj * 16 + (lane & 15);
        ib[nj] = r * 32 + (((lane >> 4) ^ ((r >> 1) & 3)) << 3);
    }

    const int nk = K >> 5;
    #pragma unroll
    for (int p = 0; p < 3; ++p) {
        if (p < nk) {
            const int ko = p * 32;
            gload16(gA0 + ko, AsB + p * 4096 + la0);
            gload16(gA1 + ko, AsB + p * 4096 + la1);
            gload16(gB0 + ko, BsB + p * 4096 + la0);
            gload16(gB1 + ko, BsB + p * 4096 + la1);
        }
    }
    int cur = 0;
    for (int it = 0; it < nk; ++it) {
        const int rem = nk - 1 - it;
        if (rem >= 2)      asm volatile("s_waitcnt vmcnt(8)" ::: "memory");
        else if (rem == 1) asm volatile("s_waitcnt vmcnt(4)" ::: "memory");
        else               asm volatile("s_waitcnt vmcnt(0)" ::: "memory");
        __builtin_amdgcn_s_barrier();
        const u16* Asc = AsB + cur * 4096;
        const u16* Bsc = BsB + cur * 4096;
        short8v av[4], bv[4];
        #pragma unroll
        for (int mi = 0; mi < 4; ++mi) av[mi] = *(const short8v*)&Asc[ia[mi]];
        #pragma unroll
        for (int nj = 0; nj < 4; ++nj) bv[nj] = *(const short8v*)&Bsc[ib[nj]];
        __builtin_amdgcn_s_setprio(1);
        #pragma unroll
        for (int mi = 0; mi < 4; ++mi)
            #pragma unroll
            for (int nj = 0; nj < 4; ++nj)
                acc[mi][nj] = __builtin_amdgcn_mfma_f32_16x16x32_bf16(
                    av[mi], bv[nj], acc[mi][nj], 0, 0, 0);
        __builtin_amdgcn_s_setprio(0);
        __builtin_amdgcn_s_barrier();
        if (it + 3 < nk) {
            const int ko = (it + 3) * 32;
            gload16(gA0 + ko, AsB + cur * 4096 + la0);
            gload16(gA1 + ko, AsB + cur * 4096 + la1);
            gload16(gB0 + ko, BsB + cur * 4096 + la0);
            gload16(gB1 + ko, BsB + cur * 4096 + la1);
        }
        cur = (cur == 2) ? 0 : cur + 1;
    }
}

// ---------------------------------------------------------------------------
// Generic GEMM kernel: C = A @ B^T + bias (f32 Cf or bf16 Cb). pairM: 1D grid,
// n = bid>>1, m = bid&1 (B-panel-adjacent for L2). cntp: skip tile + all
// writes when m0 >= *cntp.
// ---------------------------------------------------------------------------
__global__ __launch_bounds__(256) void gemm128(
    const u16* __restrict__ A, int lda,
    const u16* __restrict__ B, int ldb,
    const float* __restrict__ bias,
    float* __restrict__ Cf, u16* __restrict__ Cb, int ldc,
    int Nreal, int K, int pairM, const int* __restrict__ cntp)
{
    __shared__ __align__(16) u16 SH[24576];
    int nIdx, mIdx;
    if (pairM) { nIdx = blockIdx.x >> 1; mIdx = blockIdx.x & 1; }
    else       { nIdx = blockIdx.x;      mIdx = blockIdx.y; }
    const int m0 = mIdx * 128;
    const int n0 = nIdx * 128;
    if (cntp && m0 >= *cntp) return;

    f32x4 acc[4][4];
    #pragma unroll
    for (int i = 0; i < 4; ++i)
        #pragma unroll
        for (int j = 0; j < 4; ++j) acc[i][j] = (f32x4){0.f, 0.f, 0.f, 0.f};
    gemm_core(SH, A, lda, B, ldb, K, m0, n0, acc);

    const int lane = threadIdx.x & 63, w = threadIdx.x >> 6;
    const int wr = w >> 1, wc = w & 1;
    #pragma unroll
    for (int mi = 0; mi < 4; ++mi) {
        const int mbase = m0 + wr * 64 + mi * 16 + ((lane >> 4) << 2);
        #pragma unroll
        for (int nj = 0; nj < 4; ++nj) {
            const int n = n0 + wc * 64 + nj * 16 + (lane & 15);
            if (n >= Nreal) continue;
            const float bval = bias ? bias[n] : 0.f;
            #pragma unroll
            for (int r = 0; r < 4; ++r) {
                const int m = mbase + r;
                const float v = acc[mi][nj][r] + bval;
                if (Cb) Cb[(size_t)m * ldc + n] = f2bf(v);
                else    Cf[(size_t)m * ldc + n] = v;
            }
        }
    }
}

// ---------------------------------------------------------------------------
// G2 GEMM + fused LSTM. Grid 64: n = bid>>1 (0..31), m = bid&1.
// G2 = awe @ Wih[:,1024:]^T (gate-interleaved cols). Epilogue stages the
// 128x128 f32 patch in LDS (two 64-row halves), adds Gx[t] + Hcat[:,3072:],
// runs LSTM, updates c (fixed ownership) and writes h bf16 -> hball[t].
// ---------------------------------------------------------------------------
__global__ __launch_bounds__(256) void g2l_kernel(
    const u16* __restrict__ aweb, const u16* __restrict__ Wihb,
    const u16* __restrict__ Gxb_t, const float* __restrict__ Hcat,
    float* __restrict__ c, u16* __restrict__ hb_t,
    const int* __restrict__ cntp)
{
    __shared__ __align__(16) u16 SH[24576];
    const int bid = blockIdx.x, tid = threadIdx.x;
    const int m0 = (bid & 1) * 128, n0 = (bid >> 1) * 128;
    const int act = *cntp;
    if (m0 >= act) return;

    f32x4 acc[4][4];
    #pragma unroll
    for (int i = 0; i < 4; ++i)
        #pragma unroll
        for (int j = 0; j < 4; ++j) acc[i][j] = (f32x4){0.f, 0.f, 0.f, 0.f};
    gemm_core(SH, aweb, 2048, Wihb + 1024, 3072, 2048, m0, n0, acc);

    const int lane = tid & 63, w = tid >> 6;
    const int wr = w >> 1, wc = w & 1;
    float* patch = (float*)SH;   // 64 x 128 f32 = 32KB (gemm_core done)
    #pragma unroll
    for (int half = 0; half < 2; ++half) {
        __syncthreads();
        if (wr == half) {
            #pragma unroll
            for (int mi = 0; mi < 4; ++mi) {
                const int rbase = mi * 16 + ((lane >> 4) << 2);
                #pragma unroll
                for (int nj = 0; nj < 4; ++nj) {
                    const int col = wc * 64 + nj * 16 + (lane & 15);
                    #pragma unroll
                    for (int r = 0; r < 4; ++r)
                        patch[(rbase + r) * 128 + col] = acc[mi][nj][r];
                }
            }
        }
        __syncthreads();
        const int h0 = half * 64;
        #pragma unroll
        for (int p8 = 0; p8 < 8; ++p8) {
            const int idx = p8 * 256 + tid;
            const int row = idx >> 5, dl = idx & 31;
            const int b = m0 + h0 + row;
            if (b >= act) continue;
            const int d = (n0 >> 2) + dl;
            const float* pr = patch + row * 128 + dl * 4;
            float gi = pr[0], gf = pr[1], gg = pr[2], go = pr[3];
            const ushort4 xv = *(const ushort4*)(Gxb_t + (size_t)b * 4096 + n0 + dl * 4);
            gi += bu(xv.x); gf += bu(xv.y); gg += bu(xv.z); go += bu(xv.w);
            const float4 hv = *(const float4*)(Hcat + (size_t)b * NHC + 3072 + n0 + dl * 4);
            gi += hv.x; gf += hv.y; gg += hv.z; go += hv.w;
            float* cp = c + (size_t)b * 1024 + d;
            const float cn = sigf(gf) * cp[0] + sigf(gi) * tanhf(gg);
            const float hn = sigf(go) * tanhf(cn);
            cp[0] = cn;
            hb_t[(size_t)b * 1024 + d] = f2bf(hn);
        }
    }
}

// ---------------------------------------------------------------------------
// Batched predictions GEMM: preds[b,t,:] = hball[t,b] @ Wfc^T + bfc, zeroed
// for inactive rows. Grid (79, 40): m-tile -> (t = mt>>1, rows 128).
// ---------------------------------------------------------------------------
__global__ __launch_bounds__(256) void preds_gemm(
    const u16* __restrict__ hball, const u16* __restrict__ Wfcb,
    const float* __restrict__ bfc, const int* __restrict__ cnt,
    float* __restrict__ outP)
{
    __shared__ __align__(16) u16 SH[24576];
    const int m0 = blockIdx.y * 128;       // global row in [0, 5120)
    const int n0 = blockIdx.x * 128;
    const int t = m0 >> 8;
    const int act = cnt[t];
    const int bbase = m0 & 255;

    f32x4 acc[4][4];
    #pragma unroll
    for (int i = 0; i < 4; ++i)
        #pragma unroll
        for (int j = 0; j < 4; ++j) acc[i][j] = (f32x4){0.f, 0.f, 0.f, 0.f};
    if (bbase < act)
        gemm_core(SH, hball, 1024, Wfcb, 1024, 1024, m0, n0, acc);

    const int lane = threadIdx.x & 63, w = threadIdx.x >> 6;
    const int wr = w >> 1, wc = w & 1;
    #pragma unroll
    for (int mi = 0; mi < 4; ++mi) {
        const int mbase = bbase + wr * 64 + mi * 16 + ((lane >> 4) << 2);
        #pragma unroll
        for (int nj = 0; nj < 4; ++nj) {
            const int n = n0 + wc * 64 + nj * 16 + (lane & 15);
            if (n >= VOCAB) continue;
            const float bval = bfc[n];
            #pragma unroll
            for (int r = 0; r < 4; ++r) {
                const int b = mbase + r;
                outP[((size_t)b * TT + t) * VOCAB + n] =
                    (b < act) ? (acc[mi][nj][r] + bval) : 0.f;
            }
        }
    }
}

// ---------------------------------------------------------------------------
// Attention, z-split over obj dims: grid (B, 2). Wave-parallel softmax.
// ---------------------------------------------------------------------------
__global__ __launch_bounds__(256) void attn_kernel(
    const u16* __restrict__ att1b, const float* __restrict__ Hcat,
    const u16* __restrict__ objsb,
    const float* __restrict__ wfa, const float* __restrict__ bfa,
    const int* __restrict__ slen, int t,
    float* __restrict__ out_alph, u16* __restrict__ aweb)
{
    const int b = blockIdx.x, z = blockIdx.y, tid = threadIdx.x;
    const bool active = t < slen[b];
    if (!active) {
        if (z == 0 && tid < NOBJ)
            out_alph[((size_t)b * TT + t) * NOBJ + tid] = 0.f;
        return;
    }
    __shared__ float wred[4][40];
    __shared__ float es[40];
    __shared__ float alph[40];
    const int lane = tid & 63, w = tid >> 6;
    const float* hrow = Hcat + (size_t)b * NHC;
    const float4 h4 = ((const float4*)hrow)[tid];
    const float4 w4 = ((const float4*)wfa)[tid];
    const u16* a1base = att1b + (size_t)b * NOBJ * ATTD;

    float ep[NOBJ];
    #pragma unroll
    for (int n = 0; n < NOBJ; ++n) {
        ushort4 a4 = ((const ushort4*)(a1base + (size_t)n * ATTD))[tid];
        const float v0 = fmaxf(bu(a4.x) + h4.x, 0.f);
        const float v1 = fmaxf(bu(a4.y) + h4.y, 0.f);
        const float v2 = fmaxf(bu(a4.z) + h4.z, 0.f);
        const float v3 = fmaxf(bu(a4.w) + h4.w, 0.f);
        ep[n] = v0 * w4.x + v1 * w4.y + v2 * w4.z + v3 * w4.w;
    }
    #pragma unroll
    for (int n = 0; n < NOBJ; ++n) {
        float p = ep[n];
        #pragma unroll
        for (int off = 32; off > 0; off >>= 1) p += __shfl_down(p, off, 64);
        if (lane == 0) wred[w][n] = p;
    }
    __syncthreads();
    if (tid < NOBJ)
        es[tid] = wred[0][tid] + wred[1][tid] + wred[2][tid] + wred[3][tid] + bfa[0];
    __syncthreads();
    if (tid < 64) {
        float mv = (tid < NOBJ) ? es[tid] : -1e30f;
        #pragma unroll
        for (int off = 32; off > 0; off >>= 1) mv = fmaxf(mv, __shfl_xor(mv, off, 64));
        float e = (tid < NOBJ) ? expf(es[tid] - mv) : 0.f;
        float s = e;
        #pragma unroll
        for (int off = 32; off > 0; off >>= 1) s += __shfl_xor(s, off, 64);
        if (tid < NOBJ) alph[tid] = e / s;
    }
    __syncthreads();
    if (z == 0 && tid < NOBJ)
        out_alph[((size_t)b * TT + t) * NOBJ + tid] = alph[tid];

    float acc[4] = {0.f, 0.f, 0.f, 0.f};
    const u16* ob = objsb + (size_t)b * NOBJ * OBJD + z * 1024 + tid * 4;
    #pragma unroll 4
    for (int n = 0; n < NOBJ; ++n) {
        const ushort4 ov = *(const ushort4*)(ob + (size_t)n * OBJD);
        const float al = alph[n];
        acc[0] = fmaf(al, bu(ov.x), acc[0]);
        acc[1] = fmaf(al, bu(ov.y), acc[1]);
        acc[2] = fmaf(al, bu(ov.z), acc[2]);
        acc[3] = fmaf(al, bu(ov.w), acc[3]);
    }
    const float4 g0 = *(const float4*)(hrow + 1024 + z * 1024 + tid * 4);
    ushort4 st;
    st.x = f2bf(acc[0] * sigf(g0.x));
    st.y = f2bf(acc[1] * sigf(g0.y));
    st.z = f2bf(acc[2] * sigf(g0.z));
    st.w = f2bf(acc[3] * sigf(g0.w));
    *(ushort4*)&aweb[(size_t)b * 2048 + z * 1024 + tid * 4] = st;
}

// ---------------------------------------------------------------------------
extern "C" void kernel_launch(void* const* d_in, const int* in_sizes, int n_in,
                              void* d_out, int out_size, void* d_ws, size_t ws_size,
                              hipStream_t stream)
{
    const float* enc  = (const float*)d_in[0];
    const float* objs = (const float*)d_in[1];
    const int*   caps = (const int*)d_in[2];
    const int*   clen = (const int*)d_in[3];
    const float* emb  = (const float*)d_in[4];
    const float* Wea  = (const float*)d_in[5];
    const float* bea  = (const float*)d_in[6];
    const float* Wda  = (const float*)d_in[7];
    const float* bda  = (const float*)d_in[8];
    const float* wfa  = (const float*)d_in[9];
    const float* bfa  = (const float*)d_in[10];
    const float* Wfb  = (const float*)d_in[11];
    const float* bfb  = (const float*)d_in[12];
    const float* Wih  = (const float*)d_in[13];
    const float* Whh  = (const float*)d_in[14];
    const float* bih  = (const float*)d_in[15];
    const float* bhh  = (const float*)d_in[16];
    const float* Wfc  = (const float*)d_in[17];
    const float* bfc  = (const float*)d_in[18];

    float* outP     = (float*)d_out;                       // (B,T,V)
    float* out_caps = outP + (size_t)BB * TT * VOCAB;      // (B,T)
    float* out_len  = out_caps + BB * TT;                  // (B,)
    float* out_alph = out_len + BB;                        // (B,T,36)
    float* out_sind = out_alph + (size_t)BB * TT * NOBJ;   // (B,)

    char* wp = (char*)d_ws;
    auto alloc = [&](size_t bytes) -> void* {
        void* r = (void*)wp;
        wp += (bytes + 255) & ~(size_t)255;
        return r;
    };
    int*   sidx  = (int*)alloc(BB * 4);
    int*   slen  = (int*)alloc(BB * 4);
    int*   cnt   = (int*)alloc(32 * 4);
    u16*   objsb = (u16*)alloc((size_t)BB * NOBJ * OBJD * 2);   // 37.75 MB
    u16*   Whcb  = (u16*)alloc((size_t)NHC * 1024 * 2);         // 14.7 MB
    float* bcat  = (float*)alloc(NHC * 4);
    u16*   Wfcb  = (u16*)alloc((size_t)VOCP * 1024 * 2);        // 20.7 MB
    u16*   Wihb  = (u16*)alloc((size_t)4096 * 3072 * 2);        // 25.2 MB
    float* bsum  = (float*)alloc(4096 * 4);
    u16*   Weab  = (u16*)alloc((size_t)1024 * OBJD * 2);        // 4.2 MB
    u16*   att1b = (u16*)alloc((size_t)BB * NOBJ * ATTD * 2);   // 18.9 MB
    u16*   Xb    = (u16*)alloc((size_t)TT * BB * DECD * 2);     // 10.5 MB
    u16*   Gxb   = (u16*)alloc((size_t)TT * BB * 4096 * 2);     // 41.9 MB
    float* Hcat  = (float*)alloc((size_t)BB * NHC * 4);         // 7.3 MB
    u16*   aweb  = (u16*)alloc((size_t)BB * 2048 * 2);          // 1 MB
    u16*   hball = (u16*)alloc((size_t)TT * BB * DECD * 2);     // 10.5 MB
    float* c     = (float*)alloc((size_t)BB * DECD * 4);        // 1 MB
    (void)ws_size; (void)in_sizes; (void)n_in; (void)out_size;

    sort_kernel<<<1, 256, 0, stream>>>(clen, sidx, slen, cnt, out_len, out_sind);
    meta_kernel<<<20, 256, 0, stream>>>(caps, sidx, out_caps);
    gather_objs<<<BB * NOBJ, 256, 0, stream>>>(objs, sidx, objsb);
    convWhc<<<NHC, 256, 0, stream>>>(Wda, bda, Wfb, bfb, Whh, Whcb, bcat);
    convWfc<<<VOCP, 256, 0, stream>>>(Wfc, Wfcb);
    convWih<<<4096, 256, 0, stream>>>(Wih, bih, bhh, Wihb, bsum);
    convWea<<<1024, 256, 0, stream>>>(Wea, Weab);
    embed_kernel<<<TT * BB, 256, 0, stream>>>(enc, caps, emb, sidx, Xb);
    zero_c<<<256, 256, 0, stream>>>(c);
    hcat0_kernel<<<dim3(7, 256), 256, 0, stream>>>(bcat, Hcat);

    // att1 (bf16): M=9216, N=1024, K=2048
    gemm128<<<dim3(8, 72), 256, 0, stream>>>(
        objsb, OBJD, Weab, OBJD, bea, nullptr, att1b, ATTD,
        ATTD, OBJD, 0, nullptr);

    // Gx = X @ Wih[:, :1024]^T + bsum (bf16, gate-interleaved): M=5120, N=4096
    gemm128<<<dim3(32, 40), 256, 0, stream>>>(
        Xb, DECD, Wihb, 3072, bsum, nullptr, Gxb, 4096,
        4096, DECD, 0, nullptr);

    for (int t = 0; t < TT; ++t) {
        attn_kernel<<<dim3(BB, 2), 256, 0, stream>>>(
            att1b, Hcat, objsb, wfa, bfa, slen, t, out_alph, aweb);
        // G2 + LSTM fused: h(t) -> hball[t]
        g2l_kernel<<<64, 256, 0, stream>>>(
            aweb, Wihb, Gxb + (size_t)t * BB * 4096, Hcat, c,
            hball + (size_t)t * BB * DECD, cnt + t);
        // Hcat(t+1) = h(t) @ Whc^T + bcat (skip after last step)
        if (t < TT - 1)
            gemm128<<<112, 256, 0, stream>>>(
                hball + (size_t)t * BB * DECD, DECD, Whcb, DECD, bcat,
                Hcat, nullptr, NHC, NHC, DECD, 1, cnt + t);
    }

    // batched preds: M=5120, N=10000, K=1024
    preds_gemm<<<dim3(VOCP / 128, 40), 256, 0, stream>>>(
        hball, Wfcb, bfc, cnt, outP);
}